// Round 6
// baseline (290.026 us; speedup 1.0000x reference)
//
#include <hip/hip_runtime.h>
#include <cstdint>
#include <cstddef>

typedef __attribute__((ext_vector_type(8))) _Float16 f16x8;
typedef __attribute__((ext_vector_type(16))) float f32x16;

#define LO_SCALE 2048.0f
#define LO_INV   (1.0f / 2048.0f)

union H8 { f16x8 v; _Float16 h[8]; };

// ---------------------------------------------------------------------------
// Fused kernel A+C.
// Blocks [0,768): ka_weff_blob — Weff + direct MFMA-A-fragment blob write.
// Blocks [768,1024): kc_small — layer-0 blob + effective biases.
// whblob per (tl): [nf(8)][ks(16)][part(2)][lane(64)*8 halves]
// w0blob per t: [nf(8)][part(2)][512 halves]
// beff: [t][k(4)][256] fp32, k=0: b0+hb0, k>=1: bh[k-1]+hb[k]
// ---------------------------------------------------------------------------
__global__ __launch_bounds__(256) void kab(
    const float* __restrict__ latents, const float* __restrict__ W0,
    const float* __restrict__ b0, const float* __restrict__ bh,
    const float* __restrict__ HW0, const float* __restrict__ HB,
    const float* __restrict__ Wh, const float* __restrict__ HWh,
    _Float16* __restrict__ w0blob, float* __restrict__ beff,
    _Float16* __restrict__ whblob) {
  __shared__ float lat_t[8192];  // [k][f] : 256 x 32
  int tid = threadIdx.x, bid = blockIdx.x;

  if (bid >= 768) {
    // ---------------- kc_small ----------------
    int id = (bid - 768) * 256 + tid;
    if (id < 32768) {
      int t = id >> 10, rem = id & 1023;
      int r2 = rem & 127, part = r2 >> 6, lane = r2 & 63;
      int nf = rem >> 7;
      int o = nf * 32 + (lane & 31), kc = lane >> 5;
      const float* lat = latents + t * 256;
      H8 outv;
#pragma unroll
      for (int j = 0; j < 8; ++j) outv.h[j] = (_Float16)0.0f;
#pragma unroll
      for (int j = 0; j < 8; ++j) {
        int i = kc * 8 + j;
        if (i < 3) {
          const float* row = HW0 + (o * 3 + i) * 256;
          float s = W0[o * 3 + i];
          for (int k = 0; k < 256; k += 4)
            s += row[k] * lat[k] + row[k + 1] * lat[k + 1] +
                 row[k + 2] * lat[k + 2] + row[k + 3] * lat[k + 3];
          _Float16 hi = (_Float16)s;
          outv.h[j] = part ? (_Float16)((s - (float)hi) * LO_SCALE) : hi;
        }
      }
      *(f16x8*)(w0blob + (size_t)id * 8) = outv.v;
    } else {
      int v = id - 32768;
      int t = v >> 10, k = (v >> 8) & 3, hm = v & 255;
      float base = (k == 0) ? b0[hm] : bh[(k - 1) * 256 + hm];
      const float* lat = latents + t * 256;
      const float* row = HB + (size_t)(k * 256 + hm) * 256;
      float s = base;
      for (int kk = 0; kk < 256; kk += 4)
        s += row[kk] * lat[kk] + row[kk + 1] * lat[kk + 1] +
             row[kk + 2] * lat[kk + 2] + row[kk + 3] * lat[kk + 3];
      beff[v] = s;
    }
    return;
  }

  // ---------------- ka_weff_blob ----------------
  int h = bid & 1, ks = (bid >> 1) & 15, nf = (bid >> 5) & 7, l = bid >> 8;

  {
    int f = tid >> 3, kb = (tid & 7) * 32;
#pragma unroll
    for (int m = 0; m < 32; m += 4) {
      float4 v = *(const float4*)(latents + f * 256 + kb + m);
      lat_t[(kb + m + 0) * 32 + f] = v.x;
      lat_t[(kb + m + 1) * 32 + f] = v.y;
      lat_t[(kb + m + 2) * 32 + f] = v.z;
      lat_t[(kb + m + 3) * 32 + f] = v.w;
    }
  }
  __syncthreads();

  int oo = tid >> 3, jj = tid & 7;
  int o = nf * 32 + oo;
  int i = ks * 16 + h * 8 + jj;
  int r = o * 256 + i;
  const float* rowp = HWh + ((size_t)l * 65536 + (size_t)r) * 256;

  float acc[32];
#pragma unroll
  for (int f = 0; f < 32; ++f) acc[f] = 0.f;

  float curf[16], nxtf[16];
#pragma unroll
  for (int q = 0; q < 4; ++q)
    *(float4*)(curf + q * 4) = *(const float4*)(rowp + q * 4);

  for (int kc = 0; kc < 16; ++kc) {
    if (kc < 15) {
#pragma unroll
      for (int q = 0; q < 4; ++q)
        *(float4*)(nxtf + q * 4) = *(const float4*)(rowp + (kc + 1) * 16 + q * 4);
    }
    const float* lp = lat_t + kc * 512;
#pragma unroll
    for (int m = 0; m < 16; ++m) {
      float hw = curf[m];
#pragma unroll
      for (int fq = 0; fq < 8; ++fq) {
        float4 lv = *(const float4*)(lp + m * 32 + fq * 4);
        acc[fq * 4 + 0] += hw * lv.x;
        acc[fq * 4 + 1] += hw * lv.y;
        acc[fq * 4 + 2] += hw * lv.z;
        acc[fq * 4 + 3] += hw * lv.w;
      }
    }
#pragma unroll
    for (int q = 0; q < 16; ++q) curf[q] = nxtf[q];
  }

  float whv = Wh[l * 65536 + r];
  size_t cbase = (size_t)(nf * 16 + ks) * 1024 + (size_t)h * 256 + (size_t)tid;
#pragma unroll
  for (int t = 0; t < 32; ++t) {
    float w = acc[t] + whv;
    _Float16 hi = (_Float16)w;
    _Float16 lo = (_Float16)((w - (float)hi) * LO_SCALE);
    size_t b = (size_t)(t * 3 + l) * 131072 + cbase;
    whblob[b] = hi;
    whblob[b + 512] = lo;
  }
}

// ---------------------------------------------------------------------------
// Kernel B: fused SIREN. Block = one frame x 64 pixels, 4 waves (256 thr).
// Wave = (og = wv>>1, pg = wv&1): owns 4 A-fragments (o in og*128..+128) and
// one 32-px fragment (pg). Per ks: ONE B hi/lo LDS pair (2KB) feeds 12 MFMAs
// -> 171 B LDS per MFMA (4x under the 685 B/MFMA parity budget; R3-R5 were
// all pinned at 683 B/MFMA = LDS-BW-bound ~40% MfmaUtil).
// Transposed GEMM D[o][px] = sum_k Weff[o][k]*x[px][k], mfma_f32_32x32x16_f16
// split-fp16 (hh->accA; hl+lh (lo pre-scaled 2048)->accB; out=accA+accB/2048).
// LDS 73.7KB + <=256 VGPR -> 2 blocks/CU (decorrelated epilogue/GEMM phases).
// ---------------------------------------------------------------------------
__global__ __launch_bounds__(256, 2) void kb_siren(
    const float* __restrict__ coords, const _Float16* __restrict__ whblob,
    const _Float16* __restrict__ w0blob, const float* __restrict__ beff,
    const float* __restrict__ Wf, const float* __restrict__ bf,
    float* __restrict__ out) {
  __shared__ _Float16 xs_hi[64 * 264];
  __shared__ _Float16 xs_lo[64 * 264];
  __shared__ float wf_s[768];
  __shared__ float red[768];  // [kq(4)][px(64)][3]
  int tid = threadIdx.x;
  int bid0 = blockIdx.x;
  int bid = (bid0 & 7) * 256 + (bid0 >> 3);  // XCD swizzle: 4 frames per XCD
  int t = bid >> 6, tile = bid & 63;
  int wv = tid >> 6, lane = tid & 63, col = lane & 31, h = lane >> 5;
  int og = wv >> 1, pg = wv & 1;

  if (tid < 192) *(float4*)(wf_s + tid * 4) = *(const float4*)(Wf + tid * 4);
  if (tid < 64) {
    const float* cp = coords + (size_t)(t * 4096 + tile * 64 + tid) * 3;
    float c0 = cp[0], c1 = cp[1], c2 = cp[2];
    H8 hv, lv, z;
#pragma unroll
    for (int j = 0; j < 8; ++j) { hv.h[j] = (_Float16)0.f; lv.h[j] = (_Float16)0.f; z.h[j] = (_Float16)0.f; }
    _Float16 h0 = (_Float16)c0, h1 = (_Float16)c1, h2 = (_Float16)c2;
    hv.h[0] = h0; hv.h[1] = h1; hv.h[2] = h2;
    lv.h[0] = (_Float16)((c0 - (float)h0) * LO_SCALE);
    lv.h[1] = (_Float16)((c1 - (float)h1) * LO_SCALE);
    lv.h[2] = (_Float16)((c2 - (float)h2) * LO_SCALE);
    *(f16x8*)(xs_hi + tid * 264) = hv.v;
    *(f16x8*)(xs_lo + tid * 264) = lv.v;
    *(f16x8*)(xs_hi + tid * 264 + 8) = z.v;
    *(f16x8*)(xs_lo + tid * 264 + 8) = z.v;
  }
  __syncthreads();

  f32x16 accA[4], accB[4];  // [fr] : o-fragment index within og

  auto init_bias = [&](int bk) {
#pragma unroll
    for (int fr = 0; fr < 4; ++fr) {
      int nf = og * 4 + fr;
      const float* bp = beff + ((t * 4 + bk) << 8) + nf * 32 + h * 4;
#pragma unroll
      for (int rq = 0; rq < 4; ++rq) {
        float4 bvv = *(const float4*)(bp + rq * 8);
        float ba[4];
        *(float4*)ba = bvv;
#pragma unroll
        for (int q = 0; q < 4; ++q) {
          accA[fr][rq * 4 + q] = ba[q];
          accB[fr][rq * 4 + q] = 0.f;
        }
      }
    }
  };

  // load the wave's 4 A-fragments (hi+lo) for one ks
  auto aload = [&](const _Float16* blobL, int NS, int ks, f16x8 (&a)[4][2]) {
#pragma unroll
    for (int fr = 0; fr < 4; ++fr) {
      int nf = og * 4 + fr;
      const _Float16* p = blobL + (size_t)((nf * NS + ks) * 2) * 512 + lane * 8;
      a[fr][0] = *(const f16x8*)p;
      a[fr][1] = *(const f16x8*)(p + 512);
    }
  };

  // one ks-step: 2 LDS reads, 12 MFMAs (B reused across 4 o-fragments)
  auto mfma_ks = [&](f16x8 (&a)[4][2], int ks) {
    int off = (pg * 32 + col) * 264 + ks * 16 + h * 8;
    f16x8 bh_ = *(const f16x8*)(xs_hi + off);
    f16x8 bl_ = *(const f16x8*)(xs_lo + off);
#pragma unroll
    for (int fr = 0; fr < 4; ++fr) {
      accA[fr] = __builtin_amdgcn_mfma_f32_32x32x16_f16(a[fr][0], bh_, accA[fr], 0, 0, 0);
      accB[fr] = __builtin_amdgcn_mfma_f32_32x32x16_f16(a[fr][0], bl_, accB[fr], 0, 0, 0);
      accB[fr] = __builtin_amdgcn_mfma_f32_32x32x16_f16(a[fr][1], bh_, accB[fr], 0, 0, 0);
    }
  };

  // sine + split + in-register transpose (C rows=o -> B-frag k-contig) + store
  auto epilogue = [&]() {
#pragma unroll
    for (int fr = 0; fr < 4; ++fr)
#pragma unroll
      for (int r = 0; r < 16; ++r)
        accA[fr][r] = __sinf(fmaf(accB[fr][r], 30.0f * LO_INV, 30.0f * accA[fr][r]));
    __syncthreads();  // all waves done reading xs for this layer
#pragma unroll
    for (int fr = 0; fr < 4; ++fr)
#pragma unroll
      for (int g = 0; g < 2; ++g) {
        float seq[8];
#pragma unroll
        for (int q = 0; q < 4; ++q) {
          float oa = accA[fr][8 * g + q];       // row g*16 + q + 4h
          float ob = accA[fr][8 * g + 4 + q];   // row g*16 + 8 + q + 4h
          float send = h ? oa : ob;
          float recv = __shfl_xor(send, 32, 64);
          seq[q]     = h ? recv : oa;
          seq[4 + q] = h ? ob : recv;
        }
        H8 hv, lv;
#pragma unroll
        for (int j = 0; j < 8; ++j) {
          _Float16 hi = (_Float16)seq[j];
          hv.h[j] = hi;
          lv.h[j] = (_Float16)((seq[j] - (float)hi) * LO_SCALE);
        }
        int off = (pg * 32 + col) * 264 + (og * 4 + fr) * 32 + g * 16 + h * 8;
        *(f16x8*)(xs_hi + off) = hv.v;
        *(f16x8*)(xs_lo + off) = lv.v;
      }
    __syncthreads();
  };

  const _Float16* bl0 = whblob + (size_t)(t * 3) * 131072;
  f16x8 acur[4][2], anxt[4][2];

  // ---- layer 0 (K=16 zero-padded; coords staged in xs[.., 0..15])
  init_bias(0);
  aload(w0blob + (size_t)t * 8192, 1, 0, acur);
  mfma_ks(acur, 0);
  aload(bl0, 16, 0, acur);  // prefetch hidden L0 ks0: L2 latency under epilogue
  epilogue();

  // ---- hidden layers
#pragma unroll
  for (int li = 0; li < 3; ++li) {
    init_bias(li + 1);
    const _Float16* bl = whblob + (size_t)(t * 3 + li) * 131072;
    const _Float16* bln = whblob + (size_t)(t * 3 + li + 1) * 131072;
#pragma unroll
    for (int ks = 0; ks < 16; ++ks) {
      bool have_next = (ks < 15) || (li < 2);
      if (ks < 15) {
        aload(bl, 16, ks + 1, anxt);
      } else if (li < 2) {
        aload(bln, 16, 0, anxt);
      }
      mfma_ks(acur, ks);
      if (have_next) {
#pragma unroll
        for (int fr = 0; fr < 4; ++fr) {
          acur[fr][0] = anxt[fr][0];
          acur[fr][1] = anxt[fr][1];
        }
      }
    }
    epilogue();
  }

  // ---- final linear (3 outputs), VALU from LDS; 4 k-groups of 64
  {
    float pc0 = 0.f, pc1 = 0.f, pc2 = 0.f;
    int px = tid & 63, kq = tid >> 6;
#pragma unroll
    for (int cc = 0; cc < 8; ++cc) {
      int k0 = kq * 64 + cc * 8;
      H8 hv, lv;
      hv.v = *(const f16x8*)(xs_hi + px * 264 + k0);
      lv.v = *(const f16x8*)(xs_lo + px * 264 + k0);
#pragma unroll
      for (int j = 0; j < 8; ++j) {
        float xv = (float)hv.h[j] + (float)lv.h[j] * LO_INV;
        pc0 += xv * wf_s[k0 + j];
        pc1 += xv * wf_s[256 + k0 + j];
        pc2 += xv * wf_s[512 + k0 + j];
      }
    }
    red[kq * 192 + px * 3 + 0] = pc0;
    red[kq * 192 + px * 3 + 1] = pc1;
    red[kq * 192 + px * 3 + 2] = pc2;
    __syncthreads();
    if (tid < 192) {
      int p2 = tid / 3, c = tid - p2 * 3;
      float s = bf[c];
#pragma unroll
      for (int q = 0; q < 4; ++q) s += red[q * 192 + p2 * 3 + c];
      out[(size_t)(t * 4096 + tile * 64 + p2) * 3 + c] = s;
    }
  }
}

// ---------------------------------------------------------------------------
extern "C" void kernel_launch(void* const* d_in, const int* in_sizes, int n_in,
                              void* d_out, int out_size, void* d_ws, size_t ws_size,
                              hipStream_t stream) {
  const float* coords  = (const float*)d_in[0];
  const float* latents = (const float*)d_in[1];
  const float* W0      = (const float*)d_in[2];
  const float* b0      = (const float*)d_in[3];
  const float* Wh      = (const float*)d_in[4];
  const float* bh      = (const float*)d_in[5];
  const float* Wf      = (const float*)d_in[6];
  const float* bf      = (const float*)d_in[7];
  const float* HW0     = (const float*)d_in[8];
  const float* HWh     = (const float*)d_in[9];
  const float* HB      = (const float*)d_in[10];
  float* outp = (float*)d_out;

  char* w = (char*)d_ws;
  _Float16* whblob = (_Float16*)w;                   // 12,582,912 halves
  _Float16* w0blob = (_Float16*)(w + 25165824);      // 262,144 halves
  float*    beff   = (float*)(w + 25690112);         // 32,768 floats

  kab<<<1024, 256, 0, stream>>>(latents, W0, b0, bh, HW0, HB, Wh, HWh,
                                w0blob, beff, whblob);
  kb_siren<<<2048, 256, 0, stream>>>(coords, whblob, w0blob, beff, Wf, bf, outp);
}

// Round 7
// 230.040 us; speedup vs baseline: 1.2608x; 1.2608x over previous
//
#include <hip/hip_runtime.h>
#include <cstdint>
#include <cstddef>

typedef __attribute__((ext_vector_type(8))) _Float16 f16x8;
typedef __attribute__((ext_vector_type(16))) float f32x16;

#define LO_SCALE 2048.0f
#define LO_INV   (1.0f / 2048.0f)

union H8 { f16x8 v; _Float16 h[8]; };

// ---------------------------------------------------------------------------
// Fused kernel A+C.
// Blocks [0,768): ka_weff_blob — Weff + direct MFMA-A-fragment blob write.
// Blocks [768,1024): kc_small — layer-0 blob + effective biases.
// whblob per (tl): [nf(8)][ks(16)][part(2)][lane(64)*8 halves]
// w0blob per t: [nf(8)][part(2)][512 halves]
// beff: [t][k(4)][256] fp32, k=0: b0+hb0, k>=1: bh[k-1]+hb[k]
// ---------------------------------------------------------------------------
__global__ __launch_bounds__(256) void kab(
    const float* __restrict__ latents, const float* __restrict__ W0,
    const float* __restrict__ b0, const float* __restrict__ bh,
    const float* __restrict__ HW0, const float* __restrict__ HB,
    const float* __restrict__ Wh, const float* __restrict__ HWh,
    _Float16* __restrict__ w0blob, float* __restrict__ beff,
    _Float16* __restrict__ whblob) {
  __shared__ float lat_t[8192];  // [k][f] : 256 x 32
  int tid = threadIdx.x, bid = blockIdx.x;

  if (bid >= 768) {
    // ---------------- kc_small ----------------
    int id = (bid - 768) * 256 + tid;
    if (id < 32768) {
      int t = id >> 10, rem = id & 1023;
      int r2 = rem & 127, part = r2 >> 6, lane = r2 & 63;
      int nf = rem >> 7;
      int o = nf * 32 + (lane & 31), kc = lane >> 5;
      const float* lat = latents + t * 256;
      H8 outv;
#pragma unroll
      for (int j = 0; j < 8; ++j) outv.h[j] = (_Float16)0.0f;
#pragma unroll
      for (int j = 0; j < 8; ++j) {
        int i = kc * 8 + j;
        if (i < 3) {
          const float* row = HW0 + (o * 3 + i) * 256;
          float s = W0[o * 3 + i];
          for (int k = 0; k < 256; k += 4)
            s += row[k] * lat[k] + row[k + 1] * lat[k + 1] +
                 row[k + 2] * lat[k + 2] + row[k + 3] * lat[k + 3];
          _Float16 hi = (_Float16)s;
          outv.h[j] = part ? (_Float16)((s - (float)hi) * LO_SCALE) : hi;
        }
      }
      *(f16x8*)(w0blob + (size_t)id * 8) = outv.v;
    } else {
      int v = id - 32768;
      int t = v >> 10, k = (v >> 8) & 3, hm = v & 255;
      float base = (k == 0) ? b0[hm] : bh[(k - 1) * 256 + hm];
      const float* lat = latents + t * 256;
      const float* row = HB + (size_t)(k * 256 + hm) * 256;
      float s = base;
      for (int kk = 0; kk < 256; kk += 4)
        s += row[kk] * lat[kk] + row[kk + 1] * lat[kk + 1] +
             row[kk + 2] * lat[kk + 2] + row[kk + 3] * lat[kk + 3];
      beff[v] = s;
    }
    return;
  }

  // ---------------- ka_weff_blob ----------------
  int h = bid & 1, ks = (bid >> 1) & 15, nf = (bid >> 5) & 7, l = bid >> 8;

  {
    int f = tid >> 3, kb = (tid & 7) * 32;
#pragma unroll
    for (int m = 0; m < 32; m += 4) {
      float4 v = *(const float4*)(latents + f * 256 + kb + m);
      lat_t[(kb + m + 0) * 32 + f] = v.x;
      lat_t[(kb + m + 1) * 32 + f] = v.y;
      lat_t[(kb + m + 2) * 32 + f] = v.z;
      lat_t[(kb + m + 3) * 32 + f] = v.w;
    }
  }
  __syncthreads();

  int oo = tid >> 3, jj = tid & 7;
  int o = nf * 32 + oo;
  int i = ks * 16 + h * 8 + jj;
  int r = o * 256 + i;
  const float* rowp = HWh + ((size_t)l * 65536 + (size_t)r) * 256;

  float acc[32];
#pragma unroll
  for (int f = 0; f < 32; ++f) acc[f] = 0.f;

  float curf[16], nxtf[16];
#pragma unroll
  for (int q = 0; q < 4; ++q)
    *(float4*)(curf + q * 4) = *(const float4*)(rowp + q * 4);

  for (int kc = 0; kc < 16; ++kc) {
    if (kc < 15) {
#pragma unroll
      for (int q = 0; q < 4; ++q)
        *(float4*)(nxtf + q * 4) = *(const float4*)(rowp + (kc + 1) * 16 + q * 4);
    }
    const float* lp = lat_t + kc * 512;
#pragma unroll
    for (int m = 0; m < 16; ++m) {
      float hw = curf[m];
#pragma unroll
      for (int fq = 0; fq < 8; ++fq) {
        float4 lv = *(const float4*)(lp + m * 32 + fq * 4);
        acc[fq * 4 + 0] += hw * lv.x;
        acc[fq * 4 + 1] += hw * lv.y;
        acc[fq * 4 + 2] += hw * lv.z;
        acc[fq * 4 + 3] += hw * lv.w;
      }
    }
#pragma unroll
    for (int q = 0; q < 16; ++q) curf[q] = nxtf[q];
  }

  float whv = Wh[l * 65536 + r];
  size_t cbase = (size_t)(nf * 16 + ks) * 1024 + (size_t)h * 256 + (size_t)tid;
#pragma unroll
  for (int t = 0; t < 32; ++t) {
    float w = acc[t] + whv;
    _Float16 hi = (_Float16)w;
    _Float16 lo = (_Float16)((w - (float)hi) * LO_SCALE);
    size_t b = (size_t)(t * 3 + l) * 131072 + cbase;
    whblob[b] = hi;
    whblob[b + 512] = lo;
  }
}

// ---------------------------------------------------------------------------
// Kernel B: fused SIREN. Block = one frame x 64 pixels, 4 waves (256 thr).
// Wave wv owns fa=2 o-fragments (o in wv*64..+64) x fb=2 px-fragments (all
// 64 px). Per ks: 4 ds_read_b128 (B hi/lo x 2pf = 4KB LDS) + 4 global f16x8
// loads (A hi/lo x 2fr = 4KB L2) feed 12 MFMAs -> 341 B/MFMA on EACH pipe
// (LDS at 50% of 685B budget, L2-A at ~42 B/cyc/CU). R3/R5 put 683 B/MFMA
// on a single pipe (LDS resp. L2) -> pinned at 40-47% MfmaUtil.
// A ping-pong in named registers (no array copy -> no scratch spill, R6 bug).
// Transposed GEMM D[o][px] = sum_k Weff[o][k]*x[px][k], mfma_f32_32x32x16_f16
// split-fp16 (hh->accA; hl+lh (lo pre-scaled 2048)->accB; out=accA+accB/2048).
// LDS 73.7KB -> 2 blocks/CU (decorrelated epilogue/GEMM phases).
// ---------------------------------------------------------------------------
__global__ __launch_bounds__(256, 2) void kb_siren(
    const float* __restrict__ coords, const _Float16* __restrict__ whblob,
    const _Float16* __restrict__ w0blob, const float* __restrict__ beff,
    const float* __restrict__ Wf, const float* __restrict__ bf,
    float* __restrict__ out) {
  __shared__ _Float16 xs_hi[64 * 264];
  __shared__ _Float16 xs_lo[64 * 264];
  __shared__ float wf_s[768];
  __shared__ float red[768];  // [kq(4)][px(64)][3]
  int tid = threadIdx.x;
  int bid0 = blockIdx.x;
  int bid = (bid0 & 7) * 256 + (bid0 >> 3);  // XCD swizzle: 4 frames per XCD
  int t = bid >> 6, tile = bid & 63;
  int wv = tid >> 6, lane = tid & 63, col = lane & 31, h = lane >> 5;

  if (tid < 192) *(float4*)(wf_s + tid * 4) = *(const float4*)(Wf + tid * 4);
  if (tid < 64) {
    const float* cp = coords + (size_t)(t * 4096 + tile * 64 + tid) * 3;
    float c0 = cp[0], c1 = cp[1], c2 = cp[2];
    H8 hv, lv, z;
#pragma unroll
    for (int j = 0; j < 8; ++j) { hv.h[j] = (_Float16)0.f; lv.h[j] = (_Float16)0.f; z.h[j] = (_Float16)0.f; }
    _Float16 h0 = (_Float16)c0, h1 = (_Float16)c1, h2 = (_Float16)c2;
    hv.h[0] = h0; hv.h[1] = h1; hv.h[2] = h2;
    lv.h[0] = (_Float16)((c0 - (float)h0) * LO_SCALE);
    lv.h[1] = (_Float16)((c1 - (float)h1) * LO_SCALE);
    lv.h[2] = (_Float16)((c2 - (float)h2) * LO_SCALE);
    *(f16x8*)(xs_hi + tid * 264) = hv.v;
    *(f16x8*)(xs_lo + tid * 264) = lv.v;
    *(f16x8*)(xs_hi + tid * 264 + 8) = z.v;
    *(f16x8*)(xs_lo + tid * 264 + 8) = z.v;
  }
  __syncthreads();

  f32x16 accA[2][2], accB[2][2];  // [fr][pf]

  auto init_bias = [&](int bk) {
#pragma unroll
    for (int fr = 0; fr < 2; ++fr) {
      const float* bp = beff + ((t * 4 + bk) << 8) + (wv * 2 + fr) * 32 + h * 4;
#pragma unroll
      for (int rq = 0; rq < 4; ++rq) {
        float4 bvv = *(const float4*)(bp + rq * 8);
        float ba[4];
        *(float4*)ba = bvv;
#pragma unroll
        for (int q = 0; q < 4; ++q) {
          accA[fr][0][rq * 4 + q] = ba[q];
          accA[fr][1][rq * 4 + q] = ba[q];
          accB[fr][0][rq * 4 + q] = 0.f;
          accB[fr][1][rq * 4 + q] = 0.f;
        }
      }
    }
  };

  // load the wave's 2 A-fragment pairs (hi+lo) for one ks into named regs
  auto aload4 = [&](const _Float16* blobL, int NS, int ks,
                    f16x8& a0h, f16x8& a0l, f16x8& a1h, f16x8& a1l) {
    const _Float16* p0 = blobL + (size_t)(((wv * 2 + 0) * NS + ks) * 2) * 512 + lane * 8;
    const _Float16* p1 = blobL + (size_t)(((wv * 2 + 1) * NS + ks) * 2) * 512 + lane * 8;
    a0h = *(const f16x8*)p0;
    a0l = *(const f16x8*)(p0 + 512);
    a1h = *(const f16x8*)p1;
    a1l = *(const f16x8*)(p1 + 512);
  };

  // one ks-step: 4 LDS reads + 12 MFMAs (A reused across pf, B across fr)
  auto mfma_step = [&](f16x8 a0h, f16x8 a0l, f16x8 a1h, f16x8 a1l, int ks) {
#pragma unroll
    for (int pf = 0; pf < 2; ++pf) {
      int off = (pf * 32 + col) * 264 + ks * 16 + h * 8;
      f16x8 bh_ = *(const f16x8*)(xs_hi + off);
      f16x8 bl_ = *(const f16x8*)(xs_lo + off);
      accA[0][pf] = __builtin_amdgcn_mfma_f32_32x32x16_f16(a0h, bh_, accA[0][pf], 0, 0, 0);
      accB[0][pf] = __builtin_amdgcn_mfma_f32_32x32x16_f16(a0h, bl_, accB[0][pf], 0, 0, 0);
      accB[0][pf] = __builtin_amdgcn_mfma_f32_32x32x16_f16(a0l, bh_, accB[0][pf], 0, 0, 0);
      accA[1][pf] = __builtin_amdgcn_mfma_f32_32x32x16_f16(a1h, bh_, accA[1][pf], 0, 0, 0);
      accB[1][pf] = __builtin_amdgcn_mfma_f32_32x32x16_f16(a1h, bl_, accB[1][pf], 0, 0, 0);
      accB[1][pf] = __builtin_amdgcn_mfma_f32_32x32x16_f16(a1l, bh_, accB[1][pf], 0, 0, 0);
    }
  };

  // sine + split + in-register transpose (C rows=o -> B-frag k-contig) + store
  auto epilogue = [&]() {
#pragma unroll
    for (int fr = 0; fr < 2; ++fr)
#pragma unroll
      for (int pf = 0; pf < 2; ++pf)
#pragma unroll
        for (int r = 0; r < 16; ++r)
          accA[fr][pf][r] = __sinf(fmaf(accB[fr][pf][r], 30.0f * LO_INV, 30.0f * accA[fr][pf][r]));
    __syncthreads();  // all waves done reading xs for this layer
#pragma unroll
    for (int fr = 0; fr < 2; ++fr)
#pragma unroll
      for (int pf = 0; pf < 2; ++pf)
#pragma unroll
        for (int g = 0; g < 2; ++g) {
          float seq[8];
#pragma unroll
          for (int q = 0; q < 4; ++q) {
            float oa = accA[fr][pf][8 * g + q];       // row g*16 + q + 4h
            float ob = accA[fr][pf][8 * g + 4 + q];   // row g*16 + 8 + q + 4h
            float send = h ? oa : ob;
            float recv = __shfl_xor(send, 32, 64);
            seq[q]     = h ? recv : oa;
            seq[4 + q] = h ? ob : recv;
          }
          H8 hv, lv;
#pragma unroll
          for (int j = 0; j < 8; ++j) {
            _Float16 hi = (_Float16)seq[j];
            hv.h[j] = hi;
            lv.h[j] = (_Float16)((seq[j] - (float)hi) * LO_SCALE);
          }
          int off = (pf * 32 + col) * 264 + wv * 64 + fr * 32 + g * 16 + h * 8;
          *(f16x8*)(xs_hi + off) = hv.v;
          *(f16x8*)(xs_lo + off) = lv.v;
        }
    __syncthreads();
  };

  const _Float16* bl0 = whblob + (size_t)(t * 3) * 131072;
  f16x8 c0h, c0l, c1h, c1l, n0h, n0l, n1h, n1l;

  // ---- layer 0 (K=16 zero-padded; coords staged in xs[.., 0..15])
  init_bias(0);
  aload4(w0blob + (size_t)t * 8192, 1, 0, c0h, c0l, c1h, c1l);
  mfma_step(c0h, c0l, c1h, c1l, 0);
  aload4(bl0, 16, 0, c0h, c0l, c1h, c1l);  // prefetch hidden L0 ks0 under epilogue
  epilogue();

  // ---- hidden layers (ping-pong A prefetch, fully static register names)
#pragma unroll
  for (int li = 0; li < 3; ++li) {
    init_bias(li + 1);
    const _Float16* bl = whblob + (size_t)(t * 3 + li) * 131072;
    const _Float16* bln = whblob + (size_t)(t * 3 + li + 1) * 131072;
#pragma unroll
    for (int ks2 = 0; ks2 < 8; ++ks2) {
      int ksA = ks2 * 2, ksB = ks2 * 2 + 1;
      aload4(bl, 16, ksB, n0h, n0l, n1h, n1l);
      mfma_step(c0h, c0l, c1h, c1l, ksA);
      if (ksB < 15) {
        aload4(bl, 16, ksB + 1, c0h, c0l, c1h, c1l);
      } else if (li < 2) {
        aload4(bln, 16, 0, c0h, c0l, c1h, c1l);  // next layer ks0 under epilogue
      }
      mfma_step(n0h, n0l, n1h, n1l, ksB);
    }
    epilogue();
  }

  // ---- final linear (3 outputs), VALU from LDS; 4 k-groups of 64
  {
    float pc0 = 0.f, pc1 = 0.f, pc2 = 0.f;
    int px = tid & 63, kq = tid >> 6;
#pragma unroll
    for (int cc = 0; cc < 8; ++cc) {
      int k0 = kq * 64 + cc * 8;
      H8 hv, lv;
      hv.v = *(const f16x8*)(xs_hi + px * 264 + k0);
      lv.v = *(const f16x8*)(xs_lo + px * 264 + k0);
#pragma unroll
      for (int j = 0; j < 8; ++j) {
        float xv = (float)hv.h[j] + (float)lv.h[j] * LO_INV;
        pc0 += xv * wf_s[k0 + j];
        pc1 += xv * wf_s[256 + k0 + j];
        pc2 += xv * wf_s[512 + k0 + j];
      }
    }
    red[kq * 192 + px * 3 + 0] = pc0;
    red[kq * 192 + px * 3 + 1] = pc1;
    red[kq * 192 + px * 3 + 2] = pc2;
    __syncthreads();
    if (tid < 192) {
      int p2 = tid / 3, c = tid - p2 * 3;
      float s = bf[c];
#pragma unroll
      for (int q = 0; q < 4; ++q) s += red[q * 192 + p2 * 3 + c];
      out[(size_t)(t * 4096 + tile * 64 + p2) * 3 + c] = s;
    }
  }
}

// ---------------------------------------------------------------------------
extern "C" void kernel_launch(void* const* d_in, const int* in_sizes, int n_in,
                              void* d_out, int out_size, void* d_ws, size_t ws_size,
                              hipStream_t stream) {
  const float* coords  = (const float*)d_in[0];
  const float* latents = (const float*)d_in[1];
  const float* W0      = (const float*)d_in[2];
  const float* b0      = (const float*)d_in[3];
  const float* Wh      = (const float*)d_in[4];
  const float* bh      = (const float*)d_in[5];
  const float* Wf      = (const float*)d_in[6];
  const float* bf      = (const float*)d_in[7];
  const float* HW0     = (const float*)d_in[8];
  const float* HWh     = (const float*)d_in[9];
  const float* HB      = (const float*)d_in[10];
  float* outp = (float*)d_out;

  char* w = (char*)d_ws;
  _Float16* whblob = (_Float16*)w;                   // 12,582,912 halves
  _Float16* w0blob = (_Float16*)(w + 25165824);      // 262,144 halves
  float*    beff   = (float*)(w + 25690112);         // 32,768 floats

  kab<<<1024, 256, 0, stream>>>(latents, W0, b0, bh, HW0, HB, Wh, HWh,
                                w0blob, beff, whblob);
  kb_siren<<<2048, 256, 0, stream>>>(coords, whblob, w0blob, beff, Wf, bf, outp);
}

// Round 9
// 216.262 us; speedup vs baseline: 1.3411x; 1.0637x over previous
//
#include <hip/hip_runtime.h>
#include <cstdint>
#include <cstddef>

typedef __attribute__((ext_vector_type(8))) _Float16 f16x8;
typedef __attribute__((ext_vector_type(2))) __fp16 h2;
typedef __attribute__((ext_vector_type(16))) float f32x16;

#define LO_SCALE 2048.0f
#define LO_INV   (1.0f / 2048.0f)
// OMEGA/(2*pi): folded into all effective weights/biases so the activation is
// sin(2*pi*acc) = v_fract + v_sin (2 exact HW ops). Wf/bf are NOT scaled.
#define OMEGA_SC 4.774648292756860f

union H8 { f16x8 v; _Float16 h[8]; };
union U2 { h2 v[2]; uint2 u; };

// ---------------------------------------------------------------------------
// Fused kernel A+C.
// Blocks [0,768): ka_weff_blob — (OMEGA_SC*Weff) + direct A-fragment blob.
// Blocks [768,1024): kc_small — layer-0 blob + effective biases (both scaled).
// whblob per (tl): [nf(8)][ks(16)][part(2)][lane(64)*8 halves]
// w0blob per t: [nf(8)][part(2)][512 halves]
// beff: [t][k(4)][256] fp32 (scaled), k=0: b0+hb0, k>=1: bh[k-1]+hb[k]
// ---------------------------------------------------------------------------
__global__ __launch_bounds__(256) void kab(
    const float* __restrict__ latents, const float* __restrict__ W0,
    const float* __restrict__ b0, const float* __restrict__ bh,
    const float* __restrict__ HW0, const float* __restrict__ HB,
    const float* __restrict__ Wh, const float* __restrict__ HWh,
    _Float16* __restrict__ w0blob, float* __restrict__ beff,
    _Float16* __restrict__ whblob) {
  __shared__ float lat_t[8192];  // [k][f] : 256 x 32
  int tid = threadIdx.x, bid = blockIdx.x;

  if (bid >= 768) {
    // ---------------- kc_small ----------------
    int id = (bid - 768) * 256 + tid;
    if (id < 32768) {
      int t = id >> 10, rem = id & 1023;
      int r2 = rem & 127, part = r2 >> 6, lane = r2 & 63;
      int nf = rem >> 7;
      int o = nf * 32 + (lane & 31), kc = lane >> 5;
      const float* lat = latents + t * 256;
      H8 outv;
#pragma unroll
      for (int j = 0; j < 8; ++j) outv.h[j] = (_Float16)0.0f;
#pragma unroll
      for (int j = 0; j < 8; ++j) {
        int i = kc * 8 + j;
        if (i < 3) {
          const float* row = HW0 + (o * 3 + i) * 256;
          float s = W0[o * 3 + i];
          for (int k = 0; k < 256; k += 4)
            s += row[k] * lat[k] + row[k + 1] * lat[k + 1] +
                 row[k + 2] * lat[k + 2] + row[k + 3] * lat[k + 3];
          s *= OMEGA_SC;
          _Float16 hi = (_Float16)s;
          outv.h[j] = part ? (_Float16)((s - (float)hi) * LO_SCALE) : hi;
        }
      }
      *(f16x8*)(w0blob + (size_t)id * 8) = outv.v;
    } else {
      int v = id - 32768;
      int t = v >> 10, k = (v >> 8) & 3, hm = v & 255;
      float base = (k == 0) ? b0[hm] : bh[(k - 1) * 256 + hm];
      const float* lat = latents + t * 256;
      const float* row = HB + (size_t)(k * 256 + hm) * 256;
      float s = base;
      for (int kk = 0; kk < 256; kk += 4)
        s += row[kk] * lat[kk] + row[kk + 1] * lat[kk + 1] +
             row[kk + 2] * lat[kk + 2] + row[kk + 3] * lat[kk + 3];
      beff[v] = s * OMEGA_SC;
    }
    return;
  }

  // ---------------- ka_weff_blob ----------------
  int h = bid & 1, ks = (bid >> 1) & 15, nf = (bid >> 5) & 7, l = bid >> 8;

  {
    int f = tid >> 3, kb = (tid & 7) * 32;
#pragma unroll
    for (int m = 0; m < 32; m += 4) {
      float4 v = *(const float4*)(latents + f * 256 + kb + m);
      lat_t[(kb + m + 0) * 32 + f] = v.x;
      lat_t[(kb + m + 1) * 32 + f] = v.y;
      lat_t[(kb + m + 2) * 32 + f] = v.z;
      lat_t[(kb + m + 3) * 32 + f] = v.w;
    }
  }
  __syncthreads();

  int oo = tid >> 3, jj = tid & 7;
  int o = nf * 32 + oo;
  int i = ks * 16 + h * 8 + jj;
  int r = o * 256 + i;
  const float* rowp = HWh + ((size_t)l * 65536 + (size_t)r) * 256;

  float acc[32];
#pragma unroll
  for (int f = 0; f < 32; ++f) acc[f] = 0.f;

  float curf[16], nxtf[16];
#pragma unroll
  for (int q = 0; q < 4; ++q)
    *(float4*)(curf + q * 4) = *(const float4*)(rowp + q * 4);

  for (int kc = 0; kc < 16; ++kc) {
    if (kc < 15) {
#pragma unroll
      for (int q = 0; q < 4; ++q)
        *(float4*)(nxtf + q * 4) = *(const float4*)(rowp + (kc + 1) * 16 + q * 4);
    }
    const float* lp = lat_t + kc * 512;
#pragma unroll
    for (int m = 0; m < 16; ++m) {
      float hw = curf[m];
#pragma unroll
      for (int fq = 0; fq < 8; ++fq) {
        float4 lv = *(const float4*)(lp + m * 32 + fq * 4);
        acc[fq * 4 + 0] += hw * lv.x;
        acc[fq * 4 + 1] += hw * lv.y;
        acc[fq * 4 + 2] += hw * lv.z;
        acc[fq * 4 + 3] += hw * lv.w;
      }
    }
#pragma unroll
    for (int q = 0; q < 16; ++q) curf[q] = nxtf[q];
  }

  float whv = Wh[l * 65536 + r];
  size_t cbase = (size_t)(nf * 16 + ks) * 1024 + (size_t)h * 256 + (size_t)tid;
#pragma unroll
  for (int t = 0; t < 32; ++t) {
    float w = (acc[t] + whv) * OMEGA_SC;
    _Float16 hi = (_Float16)w;
    _Float16 lo = (_Float16)((w - (float)hi) * LO_SCALE);
    size_t b = (size_t)(t * 3 + l) * 131072 + cbase;
    whblob[b] = hi;
    whblob[b + 512] = lo;
  }
}

// ---------------------------------------------------------------------------
// Kernel B: fused SIREN. Block = one frame x 64 pixels, 4 waves (256 thr).
// Wave wv owns fa=2 o-fragments (o in wv*64..+64) x fb=2 px-fragments.
// Transposed GEMM D[o][px] = sum_k Weff[o][k]*x[px][k], mfma_f32_32x32x16_f16
// split-fp16 (hh->accA; hl+lh (lo pre-scaled 2048)->accB; out=accA+accB/2048).
// R7 post-mortem: wall = MFMA(159k cyc/CU) + VALU(151k) in SERIES (no pipe
// overlap; barrier phase-lock). This round cuts the VALU term ~2.5x:
//  - OMEGA folded into weights -> sine = v_fract + v_sin (exact identity)
//  - split via v_cvt_pkrtz (packed RTZ; residual exact in lo)
//  - NO shfl transpose: C-frag rows are 4-contiguous in k -> direct b64 stores
// ---------------------------------------------------------------------------
__global__ __launch_bounds__(256, 2) void kb_siren(
    const float* __restrict__ coords, const _Float16* __restrict__ whblob,
    const _Float16* __restrict__ w0blob, const float* __restrict__ beff,
    const float* __restrict__ Wf, const float* __restrict__ bf,
    float* __restrict__ out) {
  __shared__ _Float16 xs_hi[64 * 264];
  __shared__ _Float16 xs_lo[64 * 264];
  __shared__ float wf_s[768];
  __shared__ float red[768];  // [kq(4)][px(64)][3]
  int tid = threadIdx.x;
  int bid0 = blockIdx.x;
  int bid = (bid0 & 7) * 256 + (bid0 >> 3);  // XCD swizzle: 4 frames per XCD
  int t = bid >> 6, tile = bid & 63;
  int wv = tid >> 6, lane = tid & 63, col = lane & 31, h = lane >> 5;

  if (tid < 192) *(float4*)(wf_s + tid * 4) = *(const float4*)(Wf + tid * 4);
  if (tid < 64) {
    const float* cp = coords + (size_t)(t * 4096 + tile * 64 + tid) * 3;
    float c0 = cp[0], c1 = cp[1], c2 = cp[2];
    H8 hv, lv, z;
#pragma unroll
    for (int j = 0; j < 8; ++j) { hv.h[j] = (_Float16)0.f; lv.h[j] = (_Float16)0.f; z.h[j] = (_Float16)0.f; }
    _Float16 h0 = (_Float16)c0, h1 = (_Float16)c1, h2_ = (_Float16)c2;
    hv.h[0] = h0; hv.h[1] = h1; hv.h[2] = h2_;
    lv.h[0] = (_Float16)((c0 - (float)h0) * LO_SCALE);
    lv.h[1] = (_Float16)((c1 - (float)h1) * LO_SCALE);
    lv.h[2] = (_Float16)((c2 - (float)h2_) * LO_SCALE);
    *(f16x8*)(xs_hi + tid * 264) = hv.v;
    *(f16x8*)(xs_lo + tid * 264) = lv.v;
    *(f16x8*)(xs_hi + tid * 264 + 8) = z.v;
    *(f16x8*)(xs_lo + tid * 264 + 8) = z.v;
  }
  __syncthreads();

  f32x16 accA[2][2], accB[2][2];  // [fr][pf]

  auto init_bias = [&](int bk) {
#pragma unroll
    for (int fr = 0; fr < 2; ++fr) {
      const float* bp = beff + ((t * 4 + bk) << 8) + (wv * 2 + fr) * 32 + h * 4;
#pragma unroll
      for (int rq = 0; rq < 4; ++rq) {
        float4 bvv = *(const float4*)(bp + rq * 8);
        float ba[4];
        *(float4*)ba = bvv;
#pragma unroll
        for (int q = 0; q < 4; ++q) {
          accA[fr][0][rq * 4 + q] = ba[q];
          accA[fr][1][rq * 4 + q] = ba[q];
          accB[fr][0][rq * 4 + q] = 0.f;
          accB[fr][1][rq * 4 + q] = 0.f;
        }
      }
    }
  };

  // load the wave's 2 A-fragment pairs (hi+lo) for one ks into named regs
  auto aload4 = [&](const _Float16* blobL, int NS, int ks,
                    f16x8& a0h, f16x8& a0l, f16x8& a1h, f16x8& a1l) {
    const _Float16* p0 = blobL + (size_t)(((wv * 2 + 0) * NS + ks) * 2) * 512 + lane * 8;
    const _Float16* p1 = blobL + (size_t)(((wv * 2 + 1) * NS + ks) * 2) * 512 + lane * 8;
    a0h = *(const f16x8*)p0;
    a0l = *(const f16x8*)(p0 + 512);
    a1h = *(const f16x8*)p1;
    a1l = *(const f16x8*)(p1 + 512);
  };

  // one ks-step: 4 LDS reads + 12 MFMAs (A reused across pf, B across fr)
  auto mfma_step = [&](f16x8 a0h, f16x8 a0l, f16x8 a1h, f16x8 a1l, int ks) {
#pragma unroll
    for (int pf = 0; pf < 2; ++pf) {
      int off = (pf * 32 + col) * 264 + ks * 16 + h * 8;
      f16x8 bh_ = *(const f16x8*)(xs_hi + off);
      f16x8 bl_ = *(const f16x8*)(xs_lo + off);
      accA[0][pf] = __builtin_amdgcn_mfma_f32_32x32x16_f16(a0h, bh_, accA[0][pf], 0, 0, 0);
      accB[0][pf] = __builtin_amdgcn_mfma_f32_32x32x16_f16(a0h, bl_, accB[0][pf], 0, 0, 0);
      accB[0][pf] = __builtin_amdgcn_mfma_f32_32x32x16_f16(a0l, bh_, accB[0][pf], 0, 0, 0);
      accA[1][pf] = __builtin_amdgcn_mfma_f32_32x32x16_f16(a1h, bh_, accA[1][pf], 0, 0, 0);
      accB[1][pf] = __builtin_amdgcn_mfma_f32_32x32x16_f16(a1h, bl_, accB[1][pf], 0, 0, 0);
      accB[1][pf] = __builtin_amdgcn_mfma_f32_32x32x16_f16(a1l, bh_, accB[1][pf], 0, 0, 0);
    }
  };

  // sin(2*pi*x) via exact HW ops (weights pre-scaled by OMEGA/(2*pi))
  auto sin2pi = [](float x) {
    float f, r;
    asm("v_fract_f32 %0, %1" : "=v"(f) : "v"(x));
    asm("v_sin_f32 %0, %1" : "=v"(r) : "v"(f));
    return r;
  };

  // activation + packed RTZ split + DIRECT b64 stores (no shfl transpose):
  // C-layout rows = (reg&3) + 8*(reg>>2) + 4h -> regs 4qd..4qd+3 are rows
  // 8qd+4h+0..3, i.e. 4 k-contiguous halves = one b64 store.
  auto epilogue = [&]() {
#pragma unroll
    for (int fr = 0; fr < 2; ++fr)
#pragma unroll
      for (int pf = 0; pf < 2; ++pf)
#pragma unroll
        for (int r = 0; r < 16; ++r)
          accA[fr][pf][r] = sin2pi(fmaf(accB[fr][pf][r], LO_INV, accA[fr][pf][r]));
    __syncthreads();  // all waves done reading xs for this layer
#pragma unroll
    for (int fr = 0; fr < 2; ++fr)
#pragma unroll
      for (int pf = 0; pf < 2; ++pf) {
        int base = (pf * 32 + col) * 264 + wv * 64 + fr * 32 + h * 4;
#pragma unroll
        for (int qd = 0; qd < 4; ++qd) {
          float v0 = accA[fr][pf][qd * 4 + 0];
          float v1 = accA[fr][pf][qd * 4 + 1];
          float v2 = accA[fr][pf][qd * 4 + 2];
          float v3 = accA[fr][pf][qd * 4 + 3];
          h2 ha = __builtin_amdgcn_cvt_pkrtz(v0, v1);
          h2 hb = __builtin_amdgcn_cvt_pkrtz(v2, v3);
          float l0 = (v0 - (float)ha[0]) * LO_SCALE;
          float l1 = (v1 - (float)ha[1]) * LO_SCALE;
          float l2 = (v2 - (float)hb[0]) * LO_SCALE;
          float l3 = (v3 - (float)hb[1]) * LO_SCALE;
          h2 la = __builtin_amdgcn_cvt_pkrtz(l0, l1);
          h2 lb = __builtin_amdgcn_cvt_pkrtz(l2, l3);
          U2 uh, ul;
          uh.v[0] = ha; uh.v[1] = hb;
          ul.v[0] = la; ul.v[1] = lb;
          int off = base + qd * 8;
          *(uint2*)(xs_hi + off) = uh.u;
          *(uint2*)(xs_lo + off) = ul.u;
        }
      }
    __syncthreads();
  };

  const _Float16* bl0 = whblob + (size_t)(t * 3) * 131072;
  f16x8 c0h, c0l, c1h, c1l, n0h, n0l, n1h, n1l;

  // ---- layer 0 (K=16 zero-padded; coords staged in xs[.., 0..15])
  init_bias(0);
  aload4(w0blob + (size_t)t * 8192, 1, 0, c0h, c0l, c1h, c1l);
  mfma_step(c0h, c0l, c1h, c1l, 0);
  aload4(bl0, 16, 0, c0h, c0l, c1h, c1l);  // prefetch hidden L0 ks0 under epilogue
  epilogue();

  // ---- hidden layers (ping-pong A prefetch, fully static register names)
#pragma unroll
  for (int li = 0; li < 3; ++li) {
    init_bias(li + 1);
    const _Float16* bl = whblob + (size_t)(t * 3 + li) * 131072;
    const _Float16* bln = whblob + (size_t)(t * 3 + li + 1) * 131072;
#pragma unroll
    for (int ks2 = 0; ks2 < 8; ++ks2) {
      int ksA = ks2 * 2, ksB = ks2 * 2 + 1;
      aload4(bl, 16, ksB, n0h, n0l, n1h, n1l);
      mfma_step(c0h, c0l, c1h, c1l, ksA);
      if (ksB < 15) {
        aload4(bl, 16, ksB + 1, c0h, c0l, c1h, c1l);
      } else if (li < 2) {
        aload4(bln, 16, 0, c0h, c0l, c1h, c1l);  // next layer ks0 under epilogue
      }
      mfma_step(n0h, n0l, n1h, n1l, ksB);
    }
    epilogue();
  }

  // ---- final linear (3 outputs), VALU from LDS; 4 k-groups of 64
  {
    float pc0 = 0.f, pc1 = 0.f, pc2 = 0.f;
    int px = tid & 63, kq = tid >> 6;
#pragma unroll
    for (int cc = 0; cc < 8; ++cc) {
      int k0 = kq * 64 + cc * 8;
      H8 hv, lv;
      hv.v = *(const f16x8*)(xs_hi + px * 264 + k0);
      lv.v = *(const f16x8*)(xs_lo + px * 264 + k0);
#pragma unroll
      for (int j = 0; j < 8; ++j) {
        float xv = (float)hv.h[j] + (float)lv.h[j] * LO_INV;
        pc0 += xv * wf_s[k0 + j];
        pc1 += xv * wf_s[256 + k0 + j];
        pc2 += xv * wf_s[512 + k0 + j];
      }
    }
    red[kq * 192 + px * 3 + 0] = pc0;
    red[kq * 192 + px * 3 + 1] = pc1;
    red[kq * 192 + px * 3 + 2] = pc2;
    __syncthreads();
    if (tid < 192) {
      int p2 = tid / 3, c = tid - p2 * 3;
      float s = bf[c];
#pragma unroll
      for (int q = 0; q < 4; ++q) s += red[q * 192 + p2 * 3 + c];
      out[(size_t)(t * 4096 + tile * 64 + p2) * 3 + c] = s;
    }
  }
}

// ---------------------------------------------------------------------------
extern "C" void kernel_launch(void* const* d_in, const int* in_sizes, int n_in,
                              void* d_out, int out_size, void* d_ws, size_t ws_size,
                              hipStream_t stream) {
  const float* coords  = (const float*)d_in[0];
  const float* latents = (const float*)d_in[1];
  const float* W0      = (const float*)d_in[2];
  const float* b0      = (const float*)d_in[3];
  const float* Wh      = (const float*)d_in[4];
  const float* bh      = (const float*)d_in[5];
  const float* Wf      = (const float*)d_in[6];
  const float* bf      = (const float*)d_in[7];
  const float* HW0     = (const float*)d_in[8];
  const float* HWh     = (const float*)d_in[9];
  const float* HB      = (const float*)d_in[10];
  float* outp = (float*)d_out;

  char* w = (char*)d_ws;
  _Float16* whblob = (_Float16*)w;                   // 12,582,912 halves
  _Float16* w0blob = (_Float16*)(w + 25165824);      // 262,144 halves
  float*    beff   = (float*)(w + 25690112);         // 32,768 floats

  kab<<<1024, 256, 0, stream>>>(latents, W0, b0, bh, HW0, HB, Wh, HWh,
                                w0blob, beff, whblob);
  kb_siren<<<2048, 256, 0, stream>>>(coords, whblob, w0blob, beff, Wf, bf, outp);
}